// Round 6
// baseline (533.354 us; speedup 1.0000x reference)
//
#include <hip/hip_runtime.h>

#define BB 16
#define CC 256
#define NN 1024

typedef _Float16 f16;
typedef __attribute__((ext_vector_type(8))) _Float16 half8;   // MFMA A/B frag (4 VGPRs)
typedef __attribute__((ext_vector_type(4))) _Float16 half4_t; // 8-byte f16 load/store
typedef __attribute__((ext_vector_type(4))) float f32x4;      // MFMA C/D frag

__device__ __forceinline__ half8 ldg8(const f16* p) {
  return *reinterpret_cast<const half8*>(p);
}

// ---------------- weight transpose + f16 cast: W fp32 [ci][co] -> WThi f16 [co][ci] ----------------
struct WT5 {
  const float* s[5];
  f16* dhi[5];
};

__global__ void __launch_bounds__(256) k_transposeW(WT5 p) {
  __shared__ float tile[64][65];
  const float* s = p.s[blockIdx.z];
  f16* dhi = p.dhi[blockIdx.z];
  int r0 = blockIdx.y * 64, c0 = blockIdx.x * 64;
  int tid = threadIdx.x;
  for (int e = tid; e < 64 * 16; e += 256) {
    int r = e >> 4, c4 = (e & 15) << 2;
    float4 u = *reinterpret_cast<const float4*>(s + (size_t)(r0 + r) * 256 + c0 + c4);
    tile[r][c4 + 0] = u.x; tile[r][c4 + 1] = u.y;
    tile[r][c4 + 2] = u.z; tile[r][c4 + 3] = u.w;
  }
  __syncthreads();
  for (int e = tid; e < 64 * 16; e += 256) {
    int c = e >> 4, r4 = (e & 15) << 2;
    half4_t vh;
#pragma unroll
    for (int i = 0; i < 4; ++i) vh[i] = (f16)tile[r4 + i][c];
    *reinterpret_cast<half4_t*>(dhi + (size_t)(c0 + c) * 256 + r0 + r4) = vh;
  }
}

// ---------------- QKV: x fp32 [bg][c][n] -> qhi/khi [bl][n][c], vThi [bl][c][n] ----------------
// grid (N/32, nb), block 128 (2 waves, 16 n-rows each). 2-term: (x_hi + x_lo) * w_hi
__global__ void __launch_bounds__(128) k_qkv(const float* __restrict__ x,
    const f16* __restrict__ wqT, const f16* __restrict__ wkT, const f16* __restrict__ wvT,
    const float* __restrict__ bq, const float* __restrict__ bk, const float* __restrict__ bv,
    f16* __restrict__ qhi, f16* __restrict__ khi, f16* __restrict__ vThi, int b_base) {
  __shared__ f16 Tshi[32][264];
  __shared__ f16 Tslo[32][264];
  int bl = blockIdx.y, bg = b_base + bl, n0 = blockIdx.x * 32;
  int tid = threadIdx.x, wave = tid >> 6, lane = tid & 63;
  int row16 = lane & 15, quad = lane >> 4;

  // stage x[bg, :, n0:n0+32] transposed, split hi/lo  (256 c x 8 groups of 4 n)
#pragma unroll
  for (int e = tid; e < 2048; e += 128) {
    int c = e >> 3, n4 = (e & 7) << 2;
    float4 u = *reinterpret_cast<const float4*>(x + (size_t)(bg * CC + c) * NN + n0 + n4);
    float uv[4] = {u.x, u.y, u.z, u.w};
#pragma unroll
    for (int i = 0; i < 4; ++i) {
      f16 h = (f16)uv[i];
      Tshi[n4 + i][c] = h;
      Tslo[n4 + i][c] = (f16)(uv[i] - (float)h);
    }
  }
  __syncthreads();

  // A-frags: 16 rows per wave, K=256 (8 frags), hi + lo
  half8 ah[8], al[8];
#pragma unroll
  for (int kc = 0; kc < 8; ++kc) {
    ah[kc] = *reinterpret_cast<const half8*>(&Tshi[wave * 16 + row16][kc * 32 + quad * 8]);
    al[kc] = *reinterpret_cast<const half8*>(&Tslo[wave * 16 + row16][kc * 32 + quad * 8]);
  }

  // ---- q and k -> [bl][n][c] ----
#pragma unroll
  for (int z = 0; z < 2; ++z) {
    const f16* WT = z ? wkT : wqT;
    const float* bias = z ? bk : bq;
    f16* outp = z ? khi : qhi;
#pragma unroll
    for (int ct = 0; ct < 16; ++ct) {
      f32x4 acc = {0.f, 0.f, 0.f, 0.f};
      const f16* bh = WT + (size_t)(ct * 16 + row16) * CC + quad * 8;
#pragma unroll
      for (int kc = 0; kc < 8; ++kc) {
        half8 b = ldg8(bh + kc * 32);
        acc = __builtin_amdgcn_mfma_f32_16x16x32_f16(ah[kc], b, acc, 0, 0, 0);
        acc = __builtin_amdgcn_mfma_f32_16x16x32_f16(al[kc], b, acc, 0, 0, 0);
      }
      int co = ct * 16 + row16;
      float bb = bias[co];
#pragma unroll
      for (int r = 0; r < 4; ++r) {
        int orow = wave * 16 + quad * 4 + r;
        outp[(size_t)(bl * NN + n0 + orow) * CC + co] = (f16)(acc[r] + bb);
      }
    }
  }

  // ---- v -> transposed vThi[bl][co][n] ----
#pragma unroll
  for (int ct = 0; ct < 16; ++ct) {
    f32x4 acc = {0.f, 0.f, 0.f, 0.f};
    const f16* bh = wvT + (size_t)(ct * 16 + row16) * CC + quad * 8;
#pragma unroll
    for (int kc = 0; kc < 8; ++kc) {
      half8 b = ldg8(bh + kc * 32);
      acc = __builtin_amdgcn_mfma_f32_16x16x32_f16(ah[kc], b, acc, 0, 0, 0);
      acc = __builtin_amdgcn_mfma_f32_16x16x32_f16(al[kc], b, acc, 0, 0, 0);
    }
    int co = ct * 16 + row16;
    float bb = bv[co];
    half4_t o;
#pragma unroll
    for (int r = 0; r < 4; ++r) o[r] = (f16)(acc[r] + bb);
    *reinterpret_cast<half4_t*>(vThi + (size_t)(bl * CC + co) * NN + n0 + wave * 16 + quad * 4) = o;
  }
}

// ---------------- fused flash attention (swapped roles) + MLP(SiLU) + LayerNorm ----------------
// out[bg,j,c] = LN(MLP(sum_i softmax_i(k_j . q_i) * v[i,c]))   ; output written [bg][c][j]
// grid (N/32 j-tiles, nb), block 128 (2 waves, 16 j-rows each)
struct SmemA {
  f16 Ks[32][264];      // q-proj rows i — B operand of scores
  f16 Vts[256][40];     // vT tile [c][i] — B operand of PV
  f16 Pw[2][16][40];    // per-wave P (C->A layout round-trip)
};
struct SmemB {
  union {
    f16 e16[2][16][264];   // f16 exchange (att, h)
    float ef[2][16][132];  // fp32 exchange for output store
  };
};
union Smem {
  SmemA a;
  SmemB b_;
};

__global__ void __launch_bounds__(128) k_attn_mlp(
    const f16* __restrict__ qhi, const f16* __restrict__ khi, const f16* __restrict__ vThi,
    const f16* __restrict__ w1T, const float* __restrict__ b1,
    const f16* __restrict__ w2T, const float* __restrict__ b2,
    const float* __restrict__ gamma, const float* __restrict__ beta,
    float* __restrict__ out, int b_base) {
  __shared__ Smem sm;
  int bl = blockIdx.y, bg = b_base + bl;
  int j0 = blockIdx.x * 32;
  int tid = threadIdx.x, wave = tid >> 6, lane = tid & 63;
  int row16 = lane & 15, quad = lane >> 4;

  // A-frags: k-proj rows j, K=256
  const f16* krow = khi + (size_t)(bl * NN + j0 + wave * 16 + row16) * CC + quad * 8;
  half8 kf[8];
#pragma unroll
  for (int kc = 0; kc < 8; ++kc) kf[kc] = ldg8(krow + kc * 32);

  f32x4 O[16];
#pragma unroll
  for (int ct = 0; ct < 16; ++ct) O[ct] = {0.f, 0.f, 0.f, 0.f};
  float m_run[4], l_run[4];
#pragma unroll
  for (int r = 0; r < 4; ++r) { m_run[r] = -1e30f; l_run[r] = 0.f; }

  for (int it = 0; it < 32; ++it) {
    int i0 = it * 32;
    __syncthreads();  // prior iteration's LDS reads complete
    // stage q-proj tile: 32 x 256
#pragma unroll
    for (int e = tid; e < 2048; e += 128) {
      int i = e >> 6, c4 = (e & 63) << 2;
      *reinterpret_cast<half4_t*>(&sm.a.Ks[i][c4]) =
          *reinterpret_cast<const half4_t*>(qhi + (size_t)(bl * NN + i0 + i) * CC + c4);
    }
    // stage vT tile: 256 x 32
#pragma unroll
    for (int e = tid; e < 2048; e += 128) {
      int c = e >> 3, i4 = (e & 7) << 2;
      *reinterpret_cast<half4_t*>(&sm.a.Vts[c][i4]) =
          *reinterpret_cast<const half4_t*>(vThi + (size_t)(bl * CC + c) * NN + i0 + i4);
    }
    __syncthreads();

    // scores S[16 j][32 i]
    f32x4 s0 = {0.f, 0.f, 0.f, 0.f}, s1 = {0.f, 0.f, 0.f, 0.f};
#pragma unroll
    for (int kc = 0; kc < 8; ++kc) {
      half8 b0 = *reinterpret_cast<const half8*>(&sm.a.Ks[row16][kc * 32 + quad * 8]);
      half8 b1v = *reinterpret_cast<const half8*>(&sm.a.Ks[16 + row16][kc * 32 + quad * 8]);
      s0 = __builtin_amdgcn_mfma_f32_16x16x32_f16(kf[kc], b0, s0, 0, 0, 0);
      s1 = __builtin_amdgcn_mfma_f32_16x16x32_f16(kf[kc], b1v, s1, 0, 0, 0);
    }

    // online softmax per j-row
    float alpha[4];
#pragma unroll
    for (int r = 0; r < 4; ++r) {
      float mx = fmaxf(s0[r], s1[r]);
#pragma unroll
      for (int off = 1; off < 16; off <<= 1) mx = fmaxf(mx, __shfl_xor(mx, off, 64));
      float mnew = fmaxf(m_run[r], mx);
      alpha[r] = __expf(m_run[r] - mnew);
      m_run[r] = mnew;
      float p0 = __expf(s0[r] - mnew);
      float p1 = __expf(s1[r] - mnew);
      float sm2 = p0 + p1;
#pragma unroll
      for (int off = 1; off < 16; off <<= 1) sm2 += __shfl_xor(sm2, off, 64);
      l_run[r] = l_run[r] * alpha[r] + sm2;
      sm.a.Pw[wave][quad * 4 + r][row16] = (f16)p0;
      sm.a.Pw[wave][quad * 4 + r][16 + row16] = (f16)p1;
    }
#pragma unroll
    for (int ct = 0; ct < 16; ++ct)
#pragma unroll
      for (int r = 0; r < 4; ++r) O[ct][r] *= alpha[r];

    // PV: O[16 j][256 c] += P[16][32] @ V[32][256]  (Pw same-wave write->read; in-order LDS)
    half8 pf = *reinterpret_cast<const half8*>(&sm.a.Pw[wave][row16][quad * 8]);
#pragma unroll
    for (int ct = 0; ct < 16; ++ct) {
      half8 vf = *reinterpret_cast<const half8*>(&sm.a.Vts[ct * 16 + row16][quad * 8]);
      O[ct] = __builtin_amdgcn_mfma_f32_16x16x32_f16(pf, vf, O[ct], 0, 0, 0);
    }
  }
  __syncthreads();  // all PV reads done before exchange overwrites phase-A LDS

  // ---- phase B: MLP + LN on the 32x256 att tile (rows are wave-private) ----
  float inv[4];
#pragma unroll
  for (int r = 0; r < 4; ++r) inv[r] = 1.f / l_run[r];
#pragma unroll
  for (int ct = 0; ct < 16; ++ct)
#pragma unroll
    for (int r = 0; r < 4; ++r)
      sm.b_.e16[wave][quad * 4 + r][ct * 16 + row16] = (f16)(O[ct][r] * inv[r]);

  half8 af[8];
#pragma unroll
  for (int kc = 0; kc < 8; ++kc)
    af[kc] = *reinterpret_cast<const half8*>(&sm.b_.e16[wave][row16][kc * 32 + quad * 8]);

  // GEMM1: h = silu(att @ w1 + b1) -> e16 (own-wave rows)
#pragma unroll
  for (int ct = 0; ct < 16; ++ct) {
    f32x4 acc = {0.f, 0.f, 0.f, 0.f};
    const f16* brow = w1T + (size_t)(ct * 16 + row16) * CC + quad * 8;
#pragma unroll
    for (int kc = 0; kc < 8; ++kc)
      acc = __builtin_amdgcn_mfma_f32_16x16x32_f16(af[kc], ldg8(brow + kc * 32), acc, 0, 0, 0);
    int co = ct * 16 + row16;
    float bb = b1[co];
#pragma unroll
    for (int r = 0; r < 4; ++r) {
      float xg = acc[r] + bb;
      float h = xg / (1.f + __expf(-xg));  // SiLU
      sm.b_.e16[wave][quad * 4 + r][co] = (f16)h;
    }
  }

  half8 hf[8];
#pragma unroll
  for (int kc = 0; kc < 8; ++kc)
    hf[kc] = *reinterpret_cast<const half8*>(&sm.b_.e16[wave][row16][kc * 32 + quad * 8]);

  f32x4 acc2[16];
#pragma unroll
  for (int ct = 0; ct < 16; ++ct) {
    f32x4 acc = {0.f, 0.f, 0.f, 0.f};
    const f16* brow = w2T + (size_t)(ct * 16 + row16) * CC + quad * 8;
#pragma unroll
    for (int kc = 0; kc < 8; ++kc)
      acc = __builtin_amdgcn_mfma_f32_16x16x32_f16(hf[kc], ldg8(brow + kc * 32), acc, 0, 0, 0);
    float bb = b2[ct * 16 + row16];
#pragma unroll
    for (int r = 0; r < 4; ++r) acc[r] += bb;
    acc2[ct] = acc;
  }

  // LayerNorm over C (per-row stats via 16-lane butterfly)
  float sum[4] = {0.f, 0.f, 0.f, 0.f}, ssq[4] = {0.f, 0.f, 0.f, 0.f};
#pragma unroll
  for (int ct = 0; ct < 16; ++ct)
#pragma unroll
    for (int r = 0; r < 4; ++r) { float xv = acc2[ct][r]; sum[r] += xv; ssq[r] += xv * xv; }
  float mean[4], rstd[4];
#pragma unroll
  for (int r = 0; r < 4; ++r) {
#pragma unroll
    for (int off = 1; off < 16; off <<= 1) {
      sum[r] += __shfl_xor(sum[r], off, 64);
      ssq[r] += __shfl_xor(ssq[r], off, 64);
    }
    mean[r] = sum[r] * (1.f / 256.f);
    float var = ssq[r] * (1.f / 256.f) - mean[r] * mean[r];
    rstd[r] = rsqrtf(var + 1e-5f);
  }
#pragma unroll
  for (int ct = 0; ct < 16; ++ct) {
    int co = ct * 16 + row16;
    float g = gamma[co], be = beta[co];
#pragma unroll
    for (int r = 0; r < 4; ++r)
      acc2[ct][r] = (acc2[ct][r] - mean[r]) * rstd[r] * g + be;
  }

  // output: out[bg][c][j0+n] fp32, via two half-column passes through fp32 exchange
#pragma unroll
  for (int p = 0; p < 2; ++p) {
    __syncthreads();  // prior exchange reads complete
#pragma unroll
    for (int ct2 = 0; ct2 < 8; ++ct2) {
      int ct = p * 8 + ct2;
      int col = ct2 * 16 + row16;
#pragma unroll
      for (int r = 0; r < 4; ++r)
        sm.b_.ef[wave][quad * 4 + r][col] = acc2[ct][r];
    }
    __syncthreads();
#pragma unroll
    for (int e = tid; e < 1024; e += 128) {
      int cl = e >> 3, n4 = (e & 7) << 2;
      int w = n4 >> 4, rbase = n4 & 15;
      float4 v;
      v.x = sm.b_.ef[w][rbase + 0][cl];
      v.y = sm.b_.ef[w][rbase + 1][cl];
      v.z = sm.b_.ef[w][rbase + 2][cl];
      v.w = sm.b_.ef[w][rbase + 3][cl];
      *reinterpret_cast<float4*>(out + (size_t)(bg * CC + p * 128 + cl) * NN + j0 + n4) = v;
    }
  }
}

extern "C" void kernel_launch(void* const* d_in, const int* in_sizes, int n_in,
                              void* d_out, int out_size, void* d_ws, size_t ws_size,
                              hipStream_t stream) {
  (void)in_sizes; (void)n_in; (void)out_size;
  const float* x     = (const float*)d_in[0];
  const float* wq    = (const float*)d_in[1];
  const float* bq    = (const float*)d_in[2];
  const float* wk    = (const float*)d_in[3];
  const float* bk    = (const float*)d_in[4];
  const float* wv    = (const float*)d_in[5];
  const float* bv    = (const float*)d_in[6];
  const float* w1    = (const float*)d_in[7];
  const float* b1    = (const float*)d_in[8];
  const float* w2    = (const float*)d_in[9];
  const float* b2    = (const float*)d_in[10];
  const float* gamma = (const float*)d_in[11];
  const float* beta  = (const float*)d_in[12];
  float* out = (float*)d_out;

  // workspace (all f16): [5 weight arrays][q][k][vT] chunked over batches
  const size_t WE = 65536;               // elems per weight array
  const size_t SB = (size_t)NN * CC;     // 262,144 elems per batch per tensor
  f16* base = (f16*)d_ws;
  f16* wqT = base + 0 * WE;
  f16* wkT = base + 1 * WE;
  f16* wvT = base + 2 * WE;
  f16* w1T = base + 3 * WE;
  f16* w2T = base + 4 * WE;

  size_t wbytes = 5 * WE * sizeof(f16);            // 0.66 MB
  size_t perb   = 3 * SB * sizeof(f16);            // 1.5 MB per batch
  int nb = (ws_size > wbytes) ? (int)((ws_size - wbytes) / perb) : 1;
  if (nb < 1) nb = 1;
  if (nb > BB) nb = BB;

  f16* qb  = base + 5 * WE;
  f16* kb  = qb + (size_t)nb * SB;
  f16* vTb = kb + (size_t)nb * SB;

  WT5 p;
  p.s[0] = wq; p.s[1] = wk; p.s[2] = wv; p.s[3] = w1; p.s[4] = w2;
  p.dhi[0] = wqT; p.dhi[1] = wkT; p.dhi[2] = wvT; p.dhi[3] = w1T; p.dhi[4] = w2T;
  k_transposeW<<<dim3(4, 4, 5), 256, 0, stream>>>(p);

  for (int b0 = 0; b0 < BB; b0 += nb) {
    int cb = (b0 + nb <= BB) ? nb : (BB - b0);
    k_qkv<<<dim3(32, cb), 128, 0, stream>>>(x, wqT, wkT, wvT, bq, bk, bv, qb, kb, vTb, b0);
    k_attn_mlp<<<dim3(32, cb), 128, 0, stream>>>(qb, kb, vTb, w1T, b1, w2T, b2,
                                                 gamma, beta, out, b0);
  }
}

// Round 8
// 316.637 us; speedup vs baseline: 1.6844x; 1.6844x over previous
//
#include <hip/hip_runtime.h>

#define BB 16
#define CC 256
#define NN 1024

typedef _Float16 f16;
typedef __attribute__((ext_vector_type(8))) _Float16 half8;   // MFMA A/B frag (4 VGPRs)
typedef __attribute__((ext_vector_type(4))) _Float16 half4_t; // 8-byte f16 load/store
typedef __attribute__((ext_vector_type(4))) float f32x4;      // MFMA C/D frag

__device__ __forceinline__ half8 ldg8(const f16* p) {
  return *reinterpret_cast<const half8*>(p);
}

// ---------------- weight transpose + f16 cast: W fp32 [ci][co] -> WT f16 [co][ci] ----------------
struct WT5 {
  const float* s[5];
  f16* dhi[5];
};

__global__ void __launch_bounds__(256) k_transposeW(WT5 p) {
  __shared__ float tile[64][65];
  const float* s = p.s[blockIdx.z];
  f16* dhi = p.dhi[blockIdx.z];
  int r0 = blockIdx.y * 64, c0 = blockIdx.x * 64;
  int tid = threadIdx.x;
  for (int e = tid; e < 64 * 16; e += 256) {
    int r = e >> 4, c4 = (e & 15) << 2;
    float4 u = *reinterpret_cast<const float4*>(s + (size_t)(r0 + r) * 256 + c0 + c4);
    tile[r][c4 + 0] = u.x; tile[r][c4 + 1] = u.y;
    tile[r][c4 + 2] = u.z; tile[r][c4 + 3] = u.w;
  }
  __syncthreads();
  for (int e = tid; e < 64 * 16; e += 256) {
    int c = e >> 4, r4 = (e & 15) << 2;
    half4_t vh;
#pragma unroll
    for (int i = 0; i < 4; ++i) vh[i] = (f16)tile[r4 + i][c];
    *reinterpret_cast<half4_t*>(dhi + (size_t)(c0 + c) * 256 + r0 + r4) = vh;
  }
}

// ---------------- QKV: one output tensor per blockIdx.z (0=q,1=k,2=vT) ----------------
// grid (N/32, nb, 3), block 128 (2 waves, 16 n-rows each). 2-term: (x_hi + x_lo) * w_hi
// Only ONE barrier pair (staging + LDS reuse); all compute/stores wave-independent.
struct QkvSmem {
  union {
    struct { f16 hi[32][264]; f16 lo[32][264]; } ts;  // x-tile transposed, hi/lo split
    f16 ex[2][16][264];                               // per-wave exchange for q/k stores
  };
};

__global__ void __launch_bounds__(128, 2) k_qkv(const float* __restrict__ x,
    const f16* __restrict__ wqT, const f16* __restrict__ wkT, const f16* __restrict__ wvT,
    const float* __restrict__ bq, const float* __restrict__ bk, const float* __restrict__ bv,
    f16* __restrict__ qo, f16* __restrict__ ko, f16* __restrict__ vT, int b_base) {
  __shared__ QkvSmem sm;
  int z = blockIdx.z;
  const f16* WT     = (z == 0) ? wqT : (z == 1) ? wkT : wvT;
  const float* bias = (z == 0) ? bq  : (z == 1) ? bk  : bv;
  int bl = blockIdx.y, bg = b_base + bl, n0 = blockIdx.x * 32;
  int tid = threadIdx.x, wave = tid >> 6, lane = tid & 63;
  int row16 = lane & 15, quad = lane >> 4;

  // stage x[bg, :, n0:n0+32] transposed + hi/lo split
#pragma unroll
  for (int e = tid; e < 2048; e += 128) {
    int c = e >> 3, n4 = (e & 7) << 2;
    float4 u = *reinterpret_cast<const float4*>(x + (size_t)(bg * CC + c) * NN + n0 + n4);
    float uv[4] = {u.x, u.y, u.z, u.w};
#pragma unroll
    for (int i = 0; i < 4; ++i) {
      f16 h = (f16)uv[i];
      sm.ts.hi[n4 + i][c] = h;
      sm.ts.lo[n4 + i][c] = (f16)(uv[i] - (float)h);
    }
  }
  __syncthreads();

  half8 ah[8], al[8];
#pragma unroll
  for (int kc = 0; kc < 8; ++kc) {
    ah[kc] = *reinterpret_cast<const half8*>(&sm.ts.hi[wave * 16 + row16][kc * 32 + quad * 8]);
    al[kc] = *reinterpret_cast<const half8*>(&sm.ts.lo[wave * 16 + row16][kc * 32 + quad * 8]);
  }
  __syncthreads();  // ts dead; its memory reused as ex below

  if (z < 2) {
    // q or k: compute, exchange via per-wave LDS, store half8 rows [bl][n][c]
    f16* outp = z ? ko : qo;
#pragma unroll
    for (int ct = 0; ct < 16; ++ct) {
      f32x4 acc = {0.f, 0.f, 0.f, 0.f};
      const f16* bh = WT + (size_t)(ct * 16 + row16) * CC + quad * 8;
#pragma unroll
      for (int kc = 0; kc < 8; ++kc) {
        half8 b = ldg8(bh + kc * 32);
        acc = __builtin_amdgcn_mfma_f32_16x16x32_f16(ah[kc], b, acc, 0, 0, 0);
        acc = __builtin_amdgcn_mfma_f32_16x16x32_f16(al[kc], b, acc, 0, 0, 0);
      }
      int co = ct * 16 + row16;
      float bb = bias[co];
#pragma unroll
      for (int r = 0; r < 4; ++r)
        sm.ex[wave][quad * 4 + r][co] = (f16)(acc[r] + bb);
    }
    // same-wave LDS write->read: in-order, no barrier needed
    const f16* exr = &sm.ex[wave][row16][0];
    f16* orow = outp + (size_t)(bl * NN + n0 + wave * 16 + row16) * CC;
#pragma unroll
    for (int k = 0; k < 8; ++k) {
      half8 hv = *reinterpret_cast<const half8*>(exr + k * 32 + quad * 8);
      *reinterpret_cast<half8*>(orow + k * 32 + quad * 8) = hv;
    }
  } else {
    // v: written transposed vT[bl][co][n] via direct half4 stores
#pragma unroll
    for (int ct = 0; ct < 16; ++ct) {
      f32x4 acc = {0.f, 0.f, 0.f, 0.f};
      const f16* bh = WT + (size_t)(ct * 16 + row16) * CC + quad * 8;
#pragma unroll
      for (int kc = 0; kc < 8; ++kc) {
        half8 b = ldg8(bh + kc * 32);
        acc = __builtin_amdgcn_mfma_f32_16x16x32_f16(ah[kc], b, acc, 0, 0, 0);
        acc = __builtin_amdgcn_mfma_f32_16x16x32_f16(al[kc], b, acc, 0, 0, 0);
      }
      int co = ct * 16 + row16;
      float bb = bias[co];
      half4_t o;
#pragma unroll
      for (int r = 0; r < 4; ++r) o[r] = (f16)(acc[r] + bb);
      *reinterpret_cast<half4_t*>(vT + (size_t)(bl * CC + co) * NN + n0 + wave * 16 + quad * 4) = o;
    }
  }
}

// ---------------- fused flash attention (swapped roles) + MLP(SiLU) + LayerNorm ----------------
// out[bg,j,c] = LN(MLP(sum_i softmax_i(k_j . q_i) * v[i,c]))   ; output written [bg][c][j]
// grid (N/64 j-tiles, nb), block 256 = 4 fully-independent waves (16 j-rows each).
// ZERO __syncthreads: B-frags (q, vT, w1T, w2T) read directly from global (L2/L3-hot);
// P and the MLP att/h exchange use per-wave LDS only (same-wave ordering).
struct AttnSmem {
  f16 P[4][16][40];     // per-wave P (C->A layout round-trip)
  f16 ex[4][16][264];   // per-wave exchange (att, h)
};

__global__ void __launch_bounds__(256) k_attn_mlp(
    const f16* __restrict__ qhi, const f16* __restrict__ khi, const f16* __restrict__ vThi,
    const f16* __restrict__ w1T, const float* __restrict__ b1,
    const f16* __restrict__ w2T, const float* __restrict__ b2,
    const float* __restrict__ gamma, const float* __restrict__ beta,
    float* __restrict__ out, int b_base) {
  __shared__ AttnSmem sm;
  int bl = blockIdx.y, bg = b_base + bl;
  int j0 = blockIdx.x * 64;
  int tid = threadIdx.x, wave = tid >> 6, lane = tid & 63;
  int row16 = lane & 15, quad = lane >> 4;
  int jw = j0 + wave * 16;  // this wave's 16 j-rows

  // A-frags: k-proj rows j, K=256
  const f16* krow = khi + (size_t)(bl * NN + jw + row16) * CC + quad * 8;
  half8 kf[8];
#pragma unroll
  for (int kc = 0; kc < 8; ++kc) kf[kc] = ldg8(krow + kc * 32);

  const f16* qbase = qhi + (size_t)bl * NN * CC;
  const f16* vbase = vThi + (size_t)bl * CC * NN;

  f32x4 O[16];
#pragma unroll
  for (int ct = 0; ct < 16; ++ct) O[ct] = {0.f, 0.f, 0.f, 0.f};
  float m_run[4], l_run[4];
#pragma unroll
  for (int r = 0; r < 4; ++r) { m_run[r] = -1e30f; l_run[r] = 0.f; }

  for (int it = 0; it < 32; ++it) {
    int i0 = it * 32;
    // scores S[16 j][32 i]: q B-frags straight from global
    f32x4 s0 = {0.f, 0.f, 0.f, 0.f}, s1 = {0.f, 0.f, 0.f, 0.f};
#pragma unroll
    for (int kc = 0; kc < 8; ++kc) {
      half8 b0  = ldg8(qbase + (size_t)(i0 + row16) * CC + kc * 32 + quad * 8);
      half8 b1v = ldg8(qbase + (size_t)(i0 + 16 + row16) * CC + kc * 32 + quad * 8);
      s0 = __builtin_amdgcn_mfma_f32_16x16x32_f16(kf[kc], b0, s0, 0, 0, 0);
      s1 = __builtin_amdgcn_mfma_f32_16x16x32_f16(kf[kc], b1v, s1, 0, 0, 0);
    }

    // online softmax per j-row (i spread over the 16 row16 lanes, 2 frags)
    float alpha[4];
#pragma unroll
    for (int r = 0; r < 4; ++r) {
      float mx = fmaxf(s0[r], s1[r]);
#pragma unroll
      for (int off = 1; off < 16; off <<= 1) mx = fmaxf(mx, __shfl_xor(mx, off, 64));
      float mnew = fmaxf(m_run[r], mx);
      alpha[r] = __expf(m_run[r] - mnew);
      m_run[r] = mnew;
      float p0 = __expf(s0[r] - mnew);
      float p1 = __expf(s1[r] - mnew);
      float sm2 = p0 + p1;
#pragma unroll
      for (int off = 1; off < 16; off <<= 1) sm2 += __shfl_xor(sm2, off, 64);
      l_run[r] = l_run[r] * alpha[r] + sm2;
      sm.P[wave][quad * 4 + r][row16]      = (f16)p0;
      sm.P[wave][quad * 4 + r][16 + row16] = (f16)p1;
    }
#pragma unroll
    for (int ct = 0; ct < 16; ++ct)
#pragma unroll
      for (int r = 0; r < 4; ++r) O[ct][r] *= alpha[r];

    // PV: O[16 j][256 c] += P[16][32] @ V[32][256]; vT B-frags straight from global
    half8 pf = *reinterpret_cast<const half8*>(&sm.P[wave][row16][quad * 8]);
#pragma unroll
    for (int ct = 0; ct < 16; ++ct) {
      half8 vf = ldg8(vbase + (size_t)(ct * 16 + row16) * NN + i0 + quad * 8);
      O[ct] = __builtin_amdgcn_mfma_f32_16x16x32_f16(pf, vf, O[ct], 0, 0, 0);
    }
  }

  // ---- MLP + LN on this wave's 16x256 att tile (per-wave LDS exchange only) ----
  float inv[4];
#pragma unroll
  for (int r = 0; r < 4; ++r) inv[r] = 1.f / l_run[r];
#pragma unroll
  for (int ct = 0; ct < 16; ++ct)
#pragma unroll
    for (int r = 0; r < 4; ++r)
      sm.ex[wave][quad * 4 + r][ct * 16 + row16] = (f16)(O[ct][r] * inv[r]);

  half8 af[8];
#pragma unroll
  for (int kc = 0; kc < 8; ++kc)
    af[kc] = *reinterpret_cast<const half8*>(&sm.ex[wave][row16][kc * 32 + quad * 8]);

  // GEMM1: h = silu(att @ w1 + b1) -> ex (own-wave rows)
#pragma unroll
  for (int ct = 0; ct < 16; ++ct) {
    f32x4 acc = {0.f, 0.f, 0.f, 0.f};
    const f16* brow = w1T + (size_t)(ct * 16 + row16) * CC + quad * 8;
#pragma unroll
    for (int kc = 0; kc < 8; ++kc)
      acc = __builtin_amdgcn_mfma_f32_16x16x32_f16(af[kc], ldg8(brow + kc * 32), acc, 0, 0, 0);
    int co = ct * 16 + row16;
    float bb = b1[co];
#pragma unroll
    for (int r = 0; r < 4; ++r) {
      float xg = acc[r] + bb;
      float h = xg / (1.f + __expf(-xg));  // SiLU
      sm.ex[wave][quad * 4 + r][co] = (f16)h;
    }
  }

  half8 hf[8];
#pragma unroll
  for (int kc = 0; kc < 8; ++kc)
    hf[kc] = *reinterpret_cast<const half8*>(&sm.ex[wave][row16][kc * 32 + quad * 8]);

  f32x4 acc2[16];
#pragma unroll
  for (int ct = 0; ct < 16; ++ct) {
    f32x4 acc = {0.f, 0.f, 0.f, 0.f};
    const f16* brow = w2T + (size_t)(ct * 16 + row16) * CC + quad * 8;
#pragma unroll
    for (int kc = 0; kc < 8; ++kc)
      acc = __builtin_amdgcn_mfma_f32_16x16x32_f16(hf[kc], ldg8(brow + kc * 32), acc, 0, 0, 0);
    float bb = b2[ct * 16 + row16];
#pragma unroll
    for (int r = 0; r < 4; ++r) acc[r] += bb;
    acc2[ct] = acc;
  }

  // LayerNorm over C (per-row stats via 16-lane butterfly)
  float sum[4] = {0.f, 0.f, 0.f, 0.f}, ssq[4] = {0.f, 0.f, 0.f, 0.f};
#pragma unroll
  for (int ct = 0; ct < 16; ++ct)
#pragma unroll
    for (int r = 0; r < 4; ++r) { float xv = acc2[ct][r]; sum[r] += xv; ssq[r] += xv * xv; }
  float mean[4], rstd[4];
#pragma unroll
  for (int r = 0; r < 4; ++r) {
#pragma unroll
    for (int off = 1; off < 16; off <<= 1) {
      sum[r] += __shfl_xor(sum[r], off, 64);
      ssq[r] += __shfl_xor(ssq[r], off, 64);
    }
    mean[r] = sum[r] * (1.f / 256.f);
    float var = ssq[r] * (1.f / 256.f) - mean[r] * mean[r];
    rstd[r] = rsqrtf(var + 1e-5f);
  }

  // direct coalesced stores: out[bg][col][jw + quad*4 .. +3] = float4
  // (for fixed col, the 4 quads of the same row16 cover j 0..15 -> full 64B lines)
#pragma unroll
  for (int ct = 0; ct < 16; ++ct) {
    int col = ct * 16 + row16;
    float g = gamma[col], be = beta[col];
    f32x4 v;
#pragma unroll
    for (int r = 0; r < 4; ++r) v[r] = (acc2[ct][r] - mean[r]) * rstd[r] * g + be;
    *reinterpret_cast<f32x4*>(out + (size_t)(bg * CC + col) * NN + jw + quad * 4) = v;
  }
}

extern "C" void kernel_launch(void* const* d_in, const int* in_sizes, int n_in,
                              void* d_out, int out_size, void* d_ws, size_t ws_size,
                              hipStream_t stream) {
  (void)in_sizes; (void)n_in; (void)out_size;
  const float* x     = (const float*)d_in[0];
  const float* wq    = (const float*)d_in[1];
  const float* bq    = (const float*)d_in[2];
  const float* wk    = (const float*)d_in[3];
  const float* bk    = (const float*)d_in[4];
  const float* wv    = (const float*)d_in[5];
  const float* bv    = (const float*)d_in[6];
  const float* w1    = (const float*)d_in[7];
  const float* b1    = (const float*)d_in[8];
  const float* w2    = (const float*)d_in[9];
  const float* b2    = (const float*)d_in[10];
  const float* gamma = (const float*)d_in[11];
  const float* beta  = (const float*)d_in[12];
  float* out = (float*)d_out;

  // workspace (all f16): [5 weight arrays][q][k][vT] chunked over batches
  const size_t WE = 65536;               // elems per weight array
  const size_t SB = (size_t)NN * CC;     // 262,144 elems per batch per tensor
  f16* base = (f16*)d_ws;
  f16* wqT = base + 0 * WE;
  f16* wkT = base + 1 * WE;
  f16* wvT = base + 2 * WE;
  f16* w1T = base + 3 * WE;
  f16* w2T = base + 4 * WE;

  size_t wbytes = 5 * WE * sizeof(f16);            // 0.66 MB
  size_t perb   = 3 * SB * sizeof(f16);            // 1.5 MB per batch
  int nb = (ws_size > wbytes) ? (int)((ws_size - wbytes) / perb) : 1;
  if (nb < 1) nb = 1;
  if (nb > BB) nb = BB;

  f16* qb  = base + 5 * WE;
  f16* kb  = qb + (size_t)nb * SB;
  f16* vTb = kb + (size_t)nb * SB;

  WT5 p;
  p.s[0] = wq; p.s[1] = wk; p.s[2] = wv; p.s[3] = w1; p.s[4] = w2;
  p.dhi[0] = wqT; p.dhi[1] = wkT; p.dhi[2] = wvT; p.dhi[3] = w1T; p.dhi[4] = w2T;
  k_transposeW<<<dim3(4, 4, 5), 256, 0, stream>>>(p);

  for (int b0 = 0; b0 < BB; b0 += nb) {
    int cb = (b0 + nb <= BB) ? nb : (BB - b0);
    k_qkv<<<dim3(32, cb, 3), 128, 0, stream>>>(x, wqT, wkT, wvT, bq, bk, bv, qb, kb, vTb, b0);
    k_attn_mlp<<<dim3(16, cb), 256, 0, stream>>>(qb, kb, vTb, w1T, b1, w2T, b2,
                                                 gamma, beta, out, b0);
  }
}

// Round 9
// 289.681 us; speedup vs baseline: 1.8412x; 1.0931x over previous
//
#include <hip/hip_runtime.h>

#define BB 16
#define CC 256
#define NN 1024

typedef _Float16 f16;
typedef __attribute__((ext_vector_type(8))) _Float16 half8;   // MFMA A/B frag (4 VGPRs)
typedef __attribute__((ext_vector_type(4))) _Float16 half4_t; // 8-byte f16 load/store
typedef __attribute__((ext_vector_type(4))) float f32x4;      // MFMA C/D frag

__device__ __forceinline__ half8 ldg8(const f16* p) {
  return *reinterpret_cast<const half8*>(p);
}

// ---------------- weight transpose + f16 cast: W fp32 [ci][co] -> WT f16 [co][ci] ----------------
struct WT5 {
  const float* s[5];
  f16* dhi[5];
};

__global__ void __launch_bounds__(256) k_transposeW(WT5 p) {
  __shared__ float tile[64][65];
  const float* s = p.s[blockIdx.z];
  f16* dhi = p.dhi[blockIdx.z];
  int r0 = blockIdx.y * 64, c0 = blockIdx.x * 64;
  int tid = threadIdx.x;
  for (int e = tid; e < 64 * 16; e += 256) {
    int r = e >> 4, c4 = (e & 15) << 2;
    float4 u = *reinterpret_cast<const float4*>(s + (size_t)(r0 + r) * 256 + c0 + c4);
    tile[r][c4 + 0] = u.x; tile[r][c4 + 1] = u.y;
    tile[r][c4 + 2] = u.z; tile[r][c4 + 3] = u.w;
  }
  __syncthreads();
  for (int e = tid; e < 64 * 16; e += 256) {
    int c = e >> 4, r4 = (e & 15) << 2;
    half4_t vh;
#pragma unroll
    for (int i = 0; i < 4; ++i) vh[i] = (f16)tile[r4 + i][c];
    *reinterpret_cast<half4_t*>(dhi + (size_t)(c0 + c) * 256 + r0 + r4) = vh;
  }
}

// ---------------- QKV: one output tensor per blockIdx.z (0=q,1=k,2=vT) ----------------
// grid (nb, N/32, 3) — batch on x for XCD locality. block 256 = 4 waves:
// g = wave>>1 selects 16-row group, h = wave&1 selects ct half (8 of 16 output col-tiles).
struct QkvSmem {
  union {
    struct { f16 hi[32][264]; f16 lo[32][264]; } ts;  // x-tile transposed, hi/lo split
    f16 ex[2][16][264];                               // per-rowgroup exchange for q/k stores
  };
};

__global__ void __launch_bounds__(256) k_qkv(const float* __restrict__ x,
    const f16* __restrict__ wqT, const f16* __restrict__ wkT, const f16* __restrict__ wvT,
    const float* __restrict__ bq, const float* __restrict__ bk, const float* __restrict__ bv,
    f16* __restrict__ qo, f16* __restrict__ ko, f16* __restrict__ vT, int b_base) {
  __shared__ QkvSmem sm;
  int z = blockIdx.z;
  const f16* WT     = (z == 0) ? wqT : (z == 1) ? wkT : wvT;
  const float* bias = (z == 0) ? bq  : (z == 1) ? bk  : bv;
  int bl = blockIdx.x, bg = b_base + bl, n0 = blockIdx.y * 32;
  int tid = threadIdx.x, wave = tid >> 6, lane = tid & 63;
  int row16 = lane & 15, quad = lane >> 4;
  int g = wave >> 1, h = wave & 1;

  // stage x[bg, :, n0:n0+32] transposed + hi/lo split
#pragma unroll
  for (int e = tid; e < 2048; e += 256) {
    int c = e >> 3, n4 = (e & 7) << 2;
    float4 u = *reinterpret_cast<const float4*>(x + (size_t)(bg * CC + c) * NN + n0 + n4);
    float uv[4] = {u.x, u.y, u.z, u.w};
#pragma unroll
    for (int i = 0; i < 4; ++i) {
      f16 hh = (f16)uv[i];
      sm.ts.hi[n4 + i][c] = hh;
      sm.ts.lo[n4 + i][c] = (f16)(uv[i] - (float)hh);
    }
  }
  __syncthreads();

  half8 ah[8], al[8];
#pragma unroll
  for (int kc = 0; kc < 8; ++kc) {
    ah[kc] = *reinterpret_cast<const half8*>(&sm.ts.hi[g * 16 + row16][kc * 32 + quad * 8]);
    al[kc] = *reinterpret_cast<const half8*>(&sm.ts.lo[g * 16 + row16][kc * 32 + quad * 8]);
  }
  __syncthreads();  // ts dead; memory reused as ex below

  if (z < 2) {
    // q or k: each wave computes its 8 ct tiles, exchange via LDS, coalesced stores
    f16* outp = z ? ko : qo;
#pragma unroll
    for (int ct8 = 0; ct8 < 8; ++ct8) {
      int ct = h * 8 + ct8;
      f32x4 acc = {0.f, 0.f, 0.f, 0.f};
      const f16* bh = WT + (size_t)(ct * 16 + row16) * CC + quad * 8;
#pragma unroll
      for (int kc = 0; kc < 8; ++kc) {
        half8 b = ldg8(bh + kc * 32);
        acc = __builtin_amdgcn_mfma_f32_16x16x32_f16(ah[kc], b, acc, 0, 0, 0);
        acc = __builtin_amdgcn_mfma_f32_16x16x32_f16(al[kc], b, acc, 0, 0, 0);
      }
      int co = ct * 16 + row16;
      float bb = bias[co];
#pragma unroll
      for (int r = 0; r < 4; ++r)
        sm.ex[g][quad * 4 + r][co] = (f16)(acc[r] + bb);
    }
    __syncthreads();  // cross-wave: h=0 and h=1 col-halves both complete
    // store: wave (g,h) stores rows of group g, col half h (16 rows x 128 cols)
    f16* orow = outp + (size_t)(bl * NN + n0 + g * 16 + row16) * CC;
#pragma unroll
    for (int k = 0; k < 4; ++k) {
      int col = h * 128 + k * 32 + quad * 8;
      half8 hv = *reinterpret_cast<const half8*>(&sm.ex[g][row16][col]);
      *reinterpret_cast<half8*>(orow + col) = hv;
    }
  } else {
    // v: written transposed vT[bl][co][n] via direct half4 stores (no barrier needed)
#pragma unroll
    for (int ct8 = 0; ct8 < 8; ++ct8) {
      int ct = h * 8 + ct8;
      f32x4 acc = {0.f, 0.f, 0.f, 0.f};
      const f16* bh = WT + (size_t)(ct * 16 + row16) * CC + quad * 8;
#pragma unroll
      for (int kc = 0; kc < 8; ++kc) {
        half8 b = ldg8(bh + kc * 32);
        acc = __builtin_amdgcn_mfma_f32_16x16x32_f16(ah[kc], b, acc, 0, 0, 0);
        acc = __builtin_amdgcn_mfma_f32_16x16x32_f16(al[kc], b, acc, 0, 0, 0);
      }
      int co = ct * 16 + row16;
      float bb = bias[co];
      half4_t o;
#pragma unroll
      for (int r = 0; r < 4; ++r) o[r] = (f16)(acc[r] + bb);
      *reinterpret_cast<half4_t*>(vT + (size_t)(bl * CC + co) * NN + n0 + g * 16 + quad * 4) = o;
    }
  }
}

// ---------------- fused flash attention (swapped roles, split-i) + MLP(SiLU) + LayerNorm ----------
// out[bg,j,c] = LN(MLP(sum_i softmax_i(k_j . q_i) * v[i,c]))   ; output written [bg][c][j]
// grid (nb, N/32) — batch on x for XCD locality. block 256 = 4 waves:
// jg = wave>>1 selects 16 j-rows, ic = wave&1 selects i-chunk [ic*512, ic*512+512).
// Per-iteration: ZERO barriers (global B-frags, per-wave P LDS). One barrier for the
// online-softmax merge of the two i-chunks; phase B runs on the ic==0 waves.
struct AttnSmem {
  f16 P[4][16][40];       // per-wave P (C->A layout round-trip)
  float Om[2][16][268];   // merge buffer (ic==1 partial O), stride 268 -> 2-way banks (free)
  float ml[2][2][16];     // per j-group: m,l per row from ic==1
  f16 ex[2][16][264];     // per j-group exchange (att, h) for phase B
};

__global__ void __launch_bounds__(256) k_attn_mlp(
    const f16* __restrict__ qhi, const f16* __restrict__ khi, const f16* __restrict__ vThi,
    const f16* __restrict__ w1T, const float* __restrict__ b1,
    const f16* __restrict__ w2T, const float* __restrict__ b2,
    const float* __restrict__ gamma, const float* __restrict__ beta,
    float* __restrict__ out, int b_base) {
  __shared__ AttnSmem sm;
  int bl = blockIdx.x, bg = b_base + bl;
  int j0 = blockIdx.y * 32;
  int tid = threadIdx.x, wave = tid >> 6, lane = tid & 63;
  int row16 = lane & 15, quad = lane >> 4;
  int jg = wave >> 1, ic = wave & 1;
  int jw = j0 + jg * 16;  // this wave-pair's 16 j-rows

  // A-frags: k-proj rows j, K=256
  const f16* krow = khi + (size_t)(bl * NN + jw + row16) * CC + quad * 8;
  half8 kf[8];
#pragma unroll
  for (int kc = 0; kc < 8; ++kc) kf[kc] = ldg8(krow + kc * 32);

  const f16* qbase = qhi + (size_t)bl * NN * CC;
  const f16* vbase = vThi + (size_t)bl * CC * NN;

  f32x4 O[16];
#pragma unroll
  for (int ct = 0; ct < 16; ++ct) O[ct] = {0.f, 0.f, 0.f, 0.f};
  float m_run[4], l_run[4];
#pragma unroll
  for (int r = 0; r < 4; ++r) { m_run[r] = -1e30f; l_run[r] = 0.f; }

  for (int it = 0; it < 16; ++it) {
    int i0 = ic * 512 + it * 32;
    // scores S[16 j][32 i]: q B-frags straight from global (L2-hot via XCD swizzle)
    f32x4 s0 = {0.f, 0.f, 0.f, 0.f}, s1 = {0.f, 0.f, 0.f, 0.f};
#pragma unroll
    for (int kc = 0; kc < 8; ++kc) {
      half8 b0  = ldg8(qbase + (size_t)(i0 + row16) * CC + kc * 32 + quad * 8);
      half8 b1v = ldg8(qbase + (size_t)(i0 + 16 + row16) * CC + kc * 32 + quad * 8);
      s0 = __builtin_amdgcn_mfma_f32_16x16x32_f16(kf[kc], b0, s0, 0, 0, 0);
      s1 = __builtin_amdgcn_mfma_f32_16x16x32_f16(kf[kc], b1v, s1, 0, 0, 0);
    }

    // online softmax per j-row (i spread over the 16 row16 lanes, 2 frags)
    float alpha[4];
#pragma unroll
    for (int r = 0; r < 4; ++r) {
      float mx = fmaxf(s0[r], s1[r]);
#pragma unroll
      for (int off = 1; off < 16; off <<= 1) mx = fmaxf(mx, __shfl_xor(mx, off, 64));
      float mnew = fmaxf(m_run[r], mx);
      alpha[r] = __expf(m_run[r] - mnew);
      m_run[r] = mnew;
      float p0 = __expf(s0[r] - mnew);
      float p1 = __expf(s1[r] - mnew);
      float sm2 = p0 + p1;
#pragma unroll
      for (int off = 1; off < 16; off <<= 1) sm2 += __shfl_xor(sm2, off, 64);
      l_run[r] = l_run[r] * alpha[r] + sm2;
      sm.P[wave][quad * 4 + r][row16]      = (f16)p0;
      sm.P[wave][quad * 4 + r][16 + row16] = (f16)p1;
    }
#pragma unroll
    for (int ct = 0; ct < 16; ++ct)
#pragma unroll
      for (int r = 0; r < 4; ++r) O[ct][r] *= alpha[r];

    // PV: O[16 j][256 c] += P[16][32] @ V[32][256]; vT B-frags straight from global
    half8 pf = *reinterpret_cast<const half8*>(&sm.P[wave][row16][quad * 8]);
#pragma unroll
    for (int ct = 0; ct < 16; ++ct) {
      half8 vf = ldg8(vbase + (size_t)(ct * 16 + row16) * NN + i0 + quad * 8);
      O[ct] = __builtin_amdgcn_mfma_f32_16x16x32_f16(pf, vf, O[ct], 0, 0, 0);
    }
  }

  // ---- merge the two i-chunks (online-softmax combine) ----
  if (ic == 1) {
#pragma unroll
    for (int ct = 0; ct < 16; ++ct)
#pragma unroll
      for (int r = 0; r < 4; ++r)
        sm.Om[jg][quad * 4 + r][ct * 16 + row16] = O[ct][r];
    if (row16 == 0) {
#pragma unroll
      for (int r = 0; r < 4; ++r) {
        sm.ml[jg][0][quad * 4 + r] = m_run[r];
        sm.ml[jg][1][quad * 4 + r] = l_run[r];
      }
    }
  }
  __syncthreads();
  if (ic == 1) return;  // no further barriers below

  float a0[4], a1[4], inv[4];
#pragma unroll
  for (int r = 0; r < 4; ++r) {
    float m1 = sm.ml[jg][0][quad * 4 + r];
    float l1 = sm.ml[jg][1][quad * 4 + r];
    float M = fmaxf(m_run[r], m1);
    a0[r] = __expf(m_run[r] - M);
    a1[r] = __expf(m1 - M);
    inv[r] = 1.f / (l_run[r] * a0[r] + l1 * a1[r]);
  }

  // ---- phase B: MLP + LN on this j-group's 16x256 att tile ----
#pragma unroll
  for (int ct = 0; ct < 16; ++ct)
#pragma unroll
    for (int r = 0; r < 4; ++r) {
      float o1 = sm.Om[jg][quad * 4 + r][ct * 16 + row16];
      sm.ex[jg][quad * 4 + r][ct * 16 + row16] =
          (f16)((O[ct][r] * a0[r] + o1 * a1[r]) * inv[r]);
    }

  half8 af[8];
#pragma unroll
  for (int kc = 0; kc < 8; ++kc)
    af[kc] = *reinterpret_cast<const half8*>(&sm.ex[jg][row16][kc * 32 + quad * 8]);

  // GEMM1: h = silu(att @ w1 + b1) -> ex (own j-group rows)
#pragma unroll
  for (int ct = 0; ct < 16; ++ct) {
    f32x4 acc = {0.f, 0.f, 0.f, 0.f};
    const f16* brow = w1T + (size_t)(ct * 16 + row16) * CC + quad * 8;
#pragma unroll
    for (int kc = 0; kc < 8; ++kc)
      acc = __builtin_amdgcn_mfma_f32_16x16x32_f16(af[kc], ldg8(brow + kc * 32), acc, 0, 0, 0);
    int co = ct * 16 + row16;
    float bb = b1[co];
#pragma unroll
    for (int r = 0; r < 4; ++r) {
      float xg = acc[r] + bb;
      float hh = xg / (1.f + __expf(-xg));  // SiLU
      sm.ex[jg][quad * 4 + r][co] = (f16)hh;
    }
  }

  half8 hf[8];
#pragma unroll
  for (int kc = 0; kc < 8; ++kc)
    hf[kc] = *reinterpret_cast<const half8*>(&sm.ex[jg][row16][kc * 32 + quad * 8]);

  f32x4 acc2[16];
#pragma unroll
  for (int ct = 0; ct < 16; ++ct) {
    f32x4 acc = {0.f, 0.f, 0.f, 0.f};
    const f16* brow = w2T + (size_t)(ct * 16 + row16) * CC + quad * 8;
#pragma unroll
    for (int kc = 0; kc < 8; ++kc)
      acc = __builtin_amdgcn_mfma_f32_16x16x32_f16(hf[kc], ldg8(brow + kc * 32), acc, 0, 0, 0);
    float bb = b2[ct * 16 + row16];
#pragma unroll
    for (int r = 0; r < 4; ++r) acc[r] += bb;
    acc2[ct] = acc;
  }

  // LayerNorm over C (per-row stats via 16-lane butterfly)
  float sum[4] = {0.f, 0.f, 0.f, 0.f}, ssq[4] = {0.f, 0.f, 0.f, 0.f};
#pragma unroll
  for (int ct = 0; ct < 16; ++ct)
#pragma unroll
    for (int r = 0; r < 4; ++r) { float xv = acc2[ct][r]; sum[r] += xv; ssq[r] += xv * xv; }
  float mean[4], rstd[4];
#pragma unroll
  for (int r = 0; r < 4; ++r) {
#pragma unroll
    for (int off = 1; off < 16; off <<= 1) {
      sum[r] += __shfl_xor(sum[r], off, 64);
      ssq[r] += __shfl_xor(ssq[r], off, 64);
    }
    mean[r] = sum[r] * (1.f / 256.f);
    float var = ssq[r] * (1.f / 256.f) - mean[r] * mean[r];
    rstd[r] = rsqrtf(var + 1e-5f);
  }

  // direct coalesced stores: out[bg][col][jw + quad*4 .. +3] = float4
#pragma unroll
  for (int ct = 0; ct < 16; ++ct) {
    int col = ct * 16 + row16;
    float g = gamma[col], be = beta[col];
    f32x4 v;
#pragma unroll
    for (int r = 0; r < 4; ++r) v[r] = (acc2[ct][r] - mean[r]) * rstd[r] * g + be;
    *reinterpret_cast<f32x4*>(out + (size_t)(bg * CC + col) * NN + jw + quad * 4) = v;
  }
}

extern "C" void kernel_launch(void* const* d_in, const int* in_sizes, int n_in,
                              void* d_out, int out_size, void* d_ws, size_t ws_size,
                              hipStream_t stream) {
  (void)in_sizes; (void)n_in; (void)out_size;
  const float* x     = (const float*)d_in[0];
  const float* wq    = (const float*)d_in[1];
  const float* bq    = (const float*)d_in[2];
  const float* wk    = (const float*)d_in[3];
  const float* bk    = (const float*)d_in[4];
  const float* wv    = (const float*)d_in[5];
  const float* bv    = (const float*)d_in[6];
  const float* w1    = (const float*)d_in[7];
  const float* b1    = (const float*)d_in[8];
  const float* w2    = (const float*)d_in[9];
  const float* b2    = (const float*)d_in[10];
  const float* gamma = (const float*)d_in[11];
  const float* beta  = (const float*)d_in[12];
  float* out = (float*)d_out;

  // workspace (all f16): [5 weight arrays][q][k][vT] chunked over batches
  const size_t WE = 65536;               // elems per weight array
  const size_t SB = (size_t)NN * CC;     // 262,144 elems per batch per tensor
  f16* base = (f16*)d_ws;
  f16* wqT = base + 0 * WE;
  f16* wkT = base + 1 * WE;
  f16* wvT = base + 2 * WE;
  f16* w1T = base + 3 * WE;
  f16* w2T = base + 4 * WE;

  size_t wbytes = 5 * WE * sizeof(f16);            // 0.66 MB
  size_t perb   = 3 * SB * sizeof(f16);            // 1.5 MB per batch
  int nb = (ws_size > wbytes) ? (int)((ws_size - wbytes) / perb) : 1;
  if (nb < 1) nb = 1;
  if (nb > BB) nb = BB;

  f16* qb  = base + 5 * WE;
  f16* kb  = qb + (size_t)nb * SB;
  f16* vTb = kb + (size_t)nb * SB;

  WT5 p;
  p.s[0] = wq; p.s[1] = wk; p.s[2] = wv; p.s[3] = w1; p.s[4] = w2;
  p.dhi[0] = wqT; p.dhi[1] = wkT; p.dhi[2] = wvT; p.dhi[3] = w1T; p.dhi[4] = w2T;
  k_transposeW<<<dim3(4, 4, 5), 256, 0, stream>>>(p);

  for (int b0 = 0; b0 < BB; b0 += nb) {
    int cb = (b0 + nb <= BB) ? nb : (BB - b0);
    // batch on gridDim.x: with cb a multiple of 8, blocks of one batch share an XCD
    k_qkv<<<dim3(cb, 32, 3), 256, 0, stream>>>(x, wqT, wkT, wvT, bq, bk, bv, qb, kb, vTb, b0);
    k_attn_mlp<<<dim3(cb, 32), 256, 0, stream>>>(qb, kb, vTb, w1T, b1, w2T, b2,
                                                 gamma, beta, out, b0);
  }
}